// Round 3
// baseline (1136.402 us; speedup 1.0000x reference)
//
#include <hip/hip_runtime.h>
#include <hip/hip_bf16.h>
#include <math.h>

#define D 20
#define NROWS 5
#define TPB 256

// Fused per-row pipeline, constants LDS-resident (filled once per block):
//   h2 = relu(x @ M + c)   with M = W^T R (DxD), c = 1 + b @ R
//   h3 = h2 @ W^T + b
//   accumulate S += sum(h3), Q += sum(h3^2)
// All constant reads are wave-uniform LDS addresses -> broadcast, 0 conflicts.
// x is streamed float4-at-a-time (no xr[][] staging array -> no spill; R1 lesson).
template <int NR>
__device__ __forceinline__ void process_rows(const float* __restrict__ xp,
                                             const float* sM, const float* sW,
                                             const float* sC, const float* sB,
                                             double& sd, double& qd) {
    float h2[NR][D];
    const float4* C4 = (const float4*)sC;
#pragma unroll
    for (int q = 0; q < D / 4; ++q) {
        float4 c = C4[q];
#pragma unroll
        for (int rr = 0; rr < NR; ++rr) {
            h2[rr][4 * q + 0] = c.x;
            h2[rr][4 * q + 1] = c.y;
            h2[rr][4 * q + 2] = c.z;
            h2[rr][4 * q + 3] = c.w;
        }
    }

    const float4* xp4 = (const float4*)xp;
    const float4* M4 = (const float4*)sM;
#pragma unroll
    for (int q = 0; q < D / 4; ++q) {
        float4 xv[NR];
#pragma unroll
        for (int rr = 0; rr < NR; ++rr) xv[rr] = xp4[rr * (D / 4) + q];
#pragma unroll
        for (int dd = 0; dd < 4; ++dd) {
            const int d = 4 * q + dd;
#pragma unroll
            for (int kq = 0; kq < D / 4; ++kq) {
                float4 m = M4[d * (D / 4) + kq];
#pragma unroll
                for (int rr = 0; rr < NR; ++rr) {
                    float xs = (dd == 0) ? xv[rr].x
                             : (dd == 1) ? xv[rr].y
                             : (dd == 2) ? xv[rr].z
                                         : xv[rr].w;
                    h2[rr][4 * kq + 0] = fmaf(xs, m.x, h2[rr][4 * kq + 0]);
                    h2[rr][4 * kq + 1] = fmaf(xs, m.y, h2[rr][4 * kq + 1]);
                    h2[rr][4 * kq + 2] = fmaf(xs, m.z, h2[rr][4 * kq + 2]);
                    h2[rr][4 * kq + 3] = fmaf(xs, m.w, h2[rr][4 * kq + 3]);
                }
            }
        }
    }

#pragma unroll
    for (int rr = 0; rr < NR; ++rr)
#pragma unroll
        for (int k = 0; k < D; ++k) h2[rr][k] = fmaxf(h2[rr][k], 0.f);

    float srow[NR], qrow[NR];
#pragma unroll
    for (int rr = 0; rr < NR; ++rr) { srow[rr] = 0.f; qrow[rr] = 0.f; }

    const float4* W4 = (const float4*)sW;
#pragma unroll
    for (int j = 0; j < D; ++j) {
        float bj = sB[j];
        float h3[NR];
#pragma unroll
        for (int rr = 0; rr < NR; ++rr) h3[rr] = bj;
#pragma unroll
        for (int kq = 0; kq < D / 4; ++kq) {
            float4 w = W4[j * (D / 4) + kq];
#pragma unroll
            for (int rr = 0; rr < NR; ++rr) {
                h3[rr] = fmaf(h2[rr][4 * kq + 0], w.x, h3[rr]);
                h3[rr] = fmaf(h2[rr][4 * kq + 1], w.y, h3[rr]);
                h3[rr] = fmaf(h2[rr][4 * kq + 2], w.z, h3[rr]);
                h3[rr] = fmaf(h2[rr][4 * kq + 3], w.w, h3[rr]);
            }
        }
#pragma unroll
        for (int rr = 0; rr < NR; ++rr) {
            srow[rr] += h3[rr];
            qrow[rr] = fmaf(h3[rr], h3[rr], qrow[rr]);
        }
    }
#pragma unroll
    for (int rr = 0; rr < NR; ++rr) {
        sd += (double)srow[rr];
        qd += (double)qrow[rr];
    }
}

__global__ void __launch_bounds__(TPB)
fancy_mlp_main(const float* __restrict__ x,
               const float* __restrict__ W,
               const float* __restrict__ bvec,
               const float* __restrict__ R,
               double* __restrict__ partS,
               double* __restrict__ partQ,
               long long nrows) {
    __shared__ __align__(16) float sM[D * D];   // M = W^T R
    __shared__ __align__(16) float sW[D * D];   // W copy
    __shared__ __align__(16) float sC[D];       // c = 1 + b @ R
    __shared__ __align__(16) float sB[D];       // b copy

    // Per-block constant build: identical fp ops in every block -> deterministic.
    for (int t = threadIdx.x; t < 2 * D * D + 2 * D; t += TPB) {
        if (t < D * D) {
            int d = t / D, k = t % D;
            float s = 0.f;
#pragma unroll
            for (int j = 0; j < D; ++j) s = fmaf(W[j * D + d], R[j * D + k], s);
            sM[t] = s;
        } else if (t < D * D + D) {
            int k = t - D * D;
            float s = 1.f;
#pragma unroll
            for (int j = 0; j < D; ++j) s = fmaf(bvec[j], R[j * D + k], s);
            sC[k] = s;
        } else if (t < 2 * D * D + D) {
            int u = t - (D * D + D);
            sW[u] = W[u];
        } else {
            sB[t - (2 * D * D + D)] = bvec[t - (2 * D * D + D)];
        }
    }
    __syncthreads();

    long long gtid = (long long)blockIdx.x * TPB + threadIdx.x;
    long long gstride = (long long)gridDim.x * TPB;
    long long ngroups = nrows / NROWS;

    double sd = 0.0, qd = 0.0;
    for (long long g = gtid; g < ngroups; g += gstride) {
        process_rows<NROWS>(x + g * (NROWS * D), sM, sW, sC, sB, sd, qd);
    }
    long long tr = ngroups * NROWS + gtid;   // nrows % NROWS == 0 here; kept for safety
    if (tr < nrows) {
        process_rows<1>(x + tr * D, sM, sW, sC, sB, sd, qd);
    }

    // wave(64) shuffle reduce, then per-block partial
#pragma unroll
    for (int off = 32; off > 0; off >>= 1) {
        sd += __shfl_down(sd, off);
        qd += __shfl_down(qd, off);
    }
    __shared__ double rS[TPB / 64], rQ[TPB / 64];
    int lane = threadIdx.x & 63;
    int wid = threadIdx.x >> 6;
    if (lane == 0) { rS[wid] = sd; rQ[wid] = qd; }
    __syncthreads();
    if (threadIdx.x == 0) {
        double S = 0.0, Q = 0.0;
#pragma unroll
        for (int w = 0; w < TPB / 64; ++w) { S += rS[w]; Q += rQ[w]; }
        partS[blockIdx.x] = S;
        partQ[blockIdx.x] = Q;
    }
}

__global__ void __launch_bounds__(256)
fancy_mlp_finish(const double* __restrict__ partS,
                 const double* __restrict__ partQ,
                 int nb, float* __restrict__ out) {
    double s = 0.0, q = 0.0;
    for (int i = threadIdx.x; i < nb; i += 256) { s += partS[i]; q += partQ[i]; }
#pragma unroll
    for (int off = 32; off > 0; off >>= 1) {
        s += __shfl_down(s, off);
        q += __shfl_down(q, off);
    }
    __shared__ double rS[4], rQ[4];
    int lane = threadIdx.x & 63;
    int wid = threadIdx.x >> 6;
    if (lane == 0) { rS[wid] = s; rQ[wid] = q; }
    __syncthreads();
    if (threadIdx.x == 0) {
        double S = rS[0] + rS[1] + rS[2] + rS[3];
        double Q = rQ[0] + rQ[1] + rQ[2] + rQ[3];
        float n = (float)sqrt(Q);
        // torch: while norm > 1: x /= 2  (halving exact in fp32)
        int k = 0;
        float nn = n;
        while (nn > 1.0f) { nn *= 0.5f; ++k; }
        float mult = (nn < 0.8f) ? 10.0f : 1.0f;
        double scale = ldexp(1.0, -k);
        out[0] = (float)(S * scale * (double)mult);
    }
}

extern "C" void kernel_launch(void* const* d_in, const int* in_sizes, int n_in,
                              void* d_out, int out_size, void* d_ws, size_t ws_size,
                              hipStream_t stream) {
    const float* x = (const float*)d_in[0];
    const float* W = (const float*)d_in[1];
    const float* b = (const float*)d_in[2];
    const float* R = (const float*)d_in[3];

    long long nrows = (long long)in_sizes[0] / D;      // 2,000,000
    long long ngroups = nrows / NROWS;                 // 400,000 (exact)
    long long want_blocks = (ngroups + TPB - 1) / TPB; // 1563
    long long maxb = (long long)(ws_size / (2 * sizeof(double)));
    long long nb = want_blocks;
    if (nb > maxb) nb = maxb;
    if (nb < 1) nb = 1;
    int nblocks = (int)nb;

    double* partS = (double*)d_ws;
    double* partQ = partS + nblocks;

    fancy_mlp_main<<<nblocks, TPB, 0, stream>>>(x, W, b, R, partS, partQ, nrows);
    fancy_mlp_finish<<<1, 256, 0, stream>>>(partS, partQ, nblocks, (float*)d_out);
}

// Round 4
// 299.763 us; speedup vs baseline: 3.7910x; 3.7910x over previous
//
#include <hip/hip_runtime.h>
#include <hip/hip_bf16.h>
#include <math.h>

#define D 20
#define NROWS 5
#define TPB 256

// Fused per-row pipeline, constants LDS-resident (filled once per block):
//   h2 = relu(x @ M + c)   with M = W^T R (DxD), c = 1 + b @ R
//   h3 = h2 @ W^T + b
//   accumulate S += sum(h3), Q += sum(h3^2)
// All constant reads are wave-uniform LDS addresses -> broadcast, 0 conflicts.
// R3 lesson: LICM hoists loop-invariant LDS loads into ~440 VGPRs -> spill.
// Fix: opaque per-iteration zero offset (asm "+v") makes the constant
// addresses formally loop-variant, forcing cheap re-reads instead of hoisting.
template <int NR>
__device__ __forceinline__ void process_rows(const float* __restrict__ xp,
                                             const float* sM, const float* sW,
                                             const float* sC, const float* sB,
                                             double& sd, double& qd) {
    float h2[NR][D];
    const float4* C4 = (const float4*)sC;
#pragma unroll
    for (int q = 0; q < D / 4; ++q) {
        float4 c = C4[q];
#pragma unroll
        for (int rr = 0; rr < NR; ++rr) {
            h2[rr][4 * q + 0] = c.x;
            h2[rr][4 * q + 1] = c.y;
            h2[rr][4 * q + 2] = c.z;
            h2[rr][4 * q + 3] = c.w;
        }
    }

    const float4* xp4 = (const float4*)xp;
    const float4* M4 = (const float4*)sM;
#pragma unroll
    for (int q = 0; q < D / 4; ++q) {
        float4 xv[NR];
#pragma unroll
        for (int rr = 0; rr < NR; ++rr) xv[rr] = xp4[rr * (D / 4) + q];
#pragma unroll
        for (int dd = 0; dd < 4; ++dd) {
            const int d = 4 * q + dd;
#pragma unroll
            for (int kq = 0; kq < D / 4; ++kq) {
                float4 m = M4[d * (D / 4) + kq];
#pragma unroll
                for (int rr = 0; rr < NR; ++rr) {
                    float xs = (dd == 0) ? xv[rr].x
                             : (dd == 1) ? xv[rr].y
                             : (dd == 2) ? xv[rr].z
                                         : xv[rr].w;
                    h2[rr][4 * kq + 0] = fmaf(xs, m.x, h2[rr][4 * kq + 0]);
                    h2[rr][4 * kq + 1] = fmaf(xs, m.y, h2[rr][4 * kq + 1]);
                    h2[rr][4 * kq + 2] = fmaf(xs, m.z, h2[rr][4 * kq + 2]);
                    h2[rr][4 * kq + 3] = fmaf(xs, m.w, h2[rr][4 * kq + 3]);
                }
            }
        }
    }

#pragma unroll
    for (int rr = 0; rr < NR; ++rr)
#pragma unroll
        for (int k = 0; k < D; ++k) h2[rr][k] = fmaxf(h2[rr][k], 0.f);

    float srow[NR], qrow[NR];
#pragma unroll
    for (int rr = 0; rr < NR; ++rr) { srow[rr] = 0.f; qrow[rr] = 0.f; }

    const float4* W4 = (const float4*)sW;
#pragma unroll
    for (int j = 0; j < D; ++j) {
        float bj = sB[j];
        float h3[NR];
#pragma unroll
        for (int rr = 0; rr < NR; ++rr) h3[rr] = bj;
#pragma unroll
        for (int kq = 0; kq < D / 4; ++kq) {
            float4 w = W4[j * (D / 4) + kq];
#pragma unroll
            for (int rr = 0; rr < NR; ++rr) {
                h3[rr] = fmaf(h2[rr][4 * kq + 0], w.x, h3[rr]);
                h3[rr] = fmaf(h2[rr][4 * kq + 1], w.y, h3[rr]);
                h3[rr] = fmaf(h2[rr][4 * kq + 2], w.z, h3[rr]);
                h3[rr] = fmaf(h2[rr][4 * kq + 3], w.w, h3[rr]);
            }
        }
#pragma unroll
        for (int rr = 0; rr < NR; ++rr) {
            srow[rr] += h3[rr];
            qrow[rr] = fmaf(h3[rr], h3[rr], qrow[rr]);
        }
    }
#pragma unroll
    for (int rr = 0; rr < NR; ++rr) {
        sd += (double)srow[rr];
        qd += (double)qrow[rr];
    }
}

__global__ void __launch_bounds__(TPB)
fancy_mlp_main(const float* __restrict__ x,
               const float* __restrict__ W,
               const float* __restrict__ bvec,
               const float* __restrict__ R,
               double* __restrict__ partS,
               double* __restrict__ partQ,
               long long nrows) {
    __shared__ __align__(16) float sM[D * D];   // M = W^T R
    __shared__ __align__(16) float sW[D * D];   // W copy
    __shared__ __align__(16) float sC[D];       // c = 1 + b @ R
    __shared__ __align__(16) float sB[D];       // b copy

    // Per-block constant build: identical fp ops in every block -> deterministic.
    for (int t = threadIdx.x; t < 2 * D * D + 2 * D; t += TPB) {
        if (t < D * D) {
            int d = t / D, k = t % D;
            float s = 0.f;
#pragma unroll
            for (int j = 0; j < D; ++j) s = fmaf(W[j * D + d], R[j * D + k], s);
            sM[t] = s;
        } else if (t < D * D + D) {
            int k = t - D * D;
            float s = 1.f;
#pragma unroll
            for (int j = 0; j < D; ++j) s = fmaf(bvec[j], R[j * D + k], s);
            sC[k] = s;
        } else if (t < 2 * D * D + D) {
            int u = t - (D * D + D);
            sW[u] = W[u];
        } else {
            sB[t - (2 * D * D + D)] = bvec[t - (2 * D * D + D)];
        }
    }
    __syncthreads();

    long long gtid = (long long)blockIdx.x * TPB + threadIdx.x;
    long long gstride = (long long)gridDim.x * TPB;
    long long ngroups = nrows / NROWS;

    double sd = 0.0, qd = 0.0;
#pragma clang loop unroll(disable)
    for (long long g = gtid; g < ngroups; g += gstride) {
        // Opaque zero, re-materialized EVERY iteration: constant addresses are
        // formally loop-variant -> LICM cannot hoist the 440 LDS floats into
        // registers (R3's spill). Costs a couple VALU ops per iteration.
        int zoff = 0;
        asm volatile("" : "+v"(zoff));
        process_rows<NROWS>(x + g * (NROWS * D),
                            sM + zoff, sW + zoff, sC + zoff, sB + zoff,
                            sd, qd);
    }
    long long tr = ngroups * NROWS + gtid;   // nrows % NROWS == 0 here; safety
    if (tr < nrows) {
        process_rows<1>(x + tr * D, sM, sW, sC, sB, sd, qd);
    }

    // wave(64) shuffle reduce, then per-block partial
#pragma unroll
    for (int off = 32; off > 0; off >>= 1) {
        sd += __shfl_down(sd, off);
        qd += __shfl_down(qd, off);
    }
    __shared__ double rS[TPB / 64], rQ[TPB / 64];
    int lane = threadIdx.x & 63;
    int wid = threadIdx.x >> 6;
    if (lane == 0) { rS[wid] = sd; rQ[wid] = qd; }
    __syncthreads();
    if (threadIdx.x == 0) {
        double S = 0.0, Q = 0.0;
#pragma unroll
        for (int w = 0; w < TPB / 64; ++w) { S += rS[w]; Q += rQ[w]; }
        partS[blockIdx.x] = S;
        partQ[blockIdx.x] = Q;
    }
}

__global__ void __launch_bounds__(256)
fancy_mlp_finish(const double* __restrict__ partS,
                 const double* __restrict__ partQ,
                 int nb, float* __restrict__ out) {
    double s = 0.0, q = 0.0;
    for (int i = threadIdx.x; i < nb; i += 256) { s += partS[i]; q += partQ[i]; }
#pragma unroll
    for (int off = 32; off > 0; off >>= 1) {
        s += __shfl_down(s, off);
        q += __shfl_down(q, off);
    }
    __shared__ double rS[4], rQ[4];
    int lane = threadIdx.x & 63;
    int wid = threadIdx.x >> 6;
    if (lane == 0) { rS[wid] = s; rQ[wid] = q; }
    __syncthreads();
    if (threadIdx.x == 0) {
        double S = rS[0] + rS[1] + rS[2] + rS[3];
        double Q = rQ[0] + rQ[1] + rQ[2] + rQ[3];
        float n = (float)sqrt(Q);
        // torch: while norm > 1: x /= 2  (halving exact in fp32)
        int k = 0;
        float nn = n;
        while (nn > 1.0f) { nn *= 0.5f; ++k; }
        float mult = (nn < 0.8f) ? 10.0f : 1.0f;
        double scale = ldexp(1.0, -k);
        out[0] = (float)(S * scale * (double)mult);
    }
}

extern "C" void kernel_launch(void* const* d_in, const int* in_sizes, int n_in,
                              void* d_out, int out_size, void* d_ws, size_t ws_size,
                              hipStream_t stream) {
    const float* x = (const float*)d_in[0];
    const float* W = (const float*)d_in[1];
    const float* b = (const float*)d_in[2];
    const float* R = (const float*)d_in[3];

    long long nrows = (long long)in_sizes[0] / D;      // 2,000,000
    long long ngroups = nrows / NROWS;                 // 400,000 (exact)
    long long want_blocks = (ngroups + TPB - 1) / TPB; // 1563
    long long maxb = (long long)(ws_size / (2 * sizeof(double)));
    long long nb = want_blocks;
    if (nb > maxb) nb = maxb;
    if (nb < 1) nb = 1;
    int nblocks = (int)nb;

    double* partS = (double*)d_ws;
    double* partQ = partS + nblocks;

    fancy_mlp_main<<<nblocks, TPB, 0, stream>>>(x, W, b, R, partS, partQ, nrows);
    fancy_mlp_finish<<<1, 256, 0, stream>>>(partS, partQ, nblocks, (float*)d_out);
}